// Round 6
// baseline (2572.944 us; speedup 1.0000x reference)
//
#include <hip/hip_runtime.h>
#include <stdint.h>

// SDFNetwork: instant-ngp hashgrid encode (L=16, F=2, T=2^19, base=16, scale=1.3819)
// + fully-fused MLP 32 -> 64 -> 64 -> 1 (bias-free, ReLU hidden, linear out), all fp32.
//
// Round 6 = round 4/5 resubmitted (both hit GPU-acquisition timeouts, never ran):
//  - encode: level-blocked (per-XCD L2 keeps one <=4MB table hot), 2 points/
//    thread -> 16 gathers in flight (was latency-bound at VALUBusy 7%).
//  - MLP: 2 points/thread -> each uniform LDS weight read serves 2 points
//    (was LDS-pipe bound).

#define NLVL 16
#define TBLSZ (1u << 19)
#define HID 64
#define ENCD 32

typedef float f32x4 __attribute__((ext_vector_type(4)));
typedef float f32x2 __attribute__((ext_vector_type(2)));

// res_l = floor(16 * 1.3819^l); levels 0..4 are dense ((res+1)^3 <= T), 5..15 hashed.
__device__ constexpr int RES[NLVL] = {16, 22, 30, 42, 58, 80, 111, 153, 212, 294,
                                      406, 561, 775, 1072, 1481, 2047};

struct Corner8 {
    uint32_t i[8];
    float w[8];
};

// Compute the 8 corner indices + trilinear weights for (x01,y01,z01) at level l.
// Index/weight order: bit2=x, bit1=y, bit0=z (z fastest) — matches rounds 1-2.
__device__ __forceinline__ void corner_idx(int l, float x01, float y01, float z01,
                                           Corner8& c)
{
    const int res = RES[l];
    const float fres = (float)res;
    const float px = x01 * fres, py = y01 * fres, pz = z01 * fres;
    const float fx = floorf(px), fy = floorf(py), fz = floorf(pz);
    const float tx = px - fx, ty = py - fy, tz = pz - fz;
    const uint32_t cx = (uint32_t)fx, cy = (uint32_t)fy, cz = (uint32_t)fz;

    if (l < 5) {
        const uint32_t s1 = (uint32_t)(res + 1);
        const uint32_t s2 = s1 * s1;
        const uint32_t bx0 = cx, bx1 = cx + 1u;
        const uint32_t by0 = cy * s1, by1 = by0 + s1;
        const uint32_t bz0 = cz * s2, bz1 = bz0 + s2;
        c.i[0] = bx0 + by0 + bz0; c.i[1] = bx0 + by0 + bz1;
        c.i[2] = bx0 + by1 + bz0; c.i[3] = bx0 + by1 + bz1;
        c.i[4] = bx1 + by0 + bz0; c.i[5] = bx1 + by0 + bz1;
        c.i[6] = bx1 + by1 + bz0; c.i[7] = bx1 + by1 + bz1;
    } else {
        const uint32_t P1 = 2654435761u, P2 = 805459861u;
        const uint32_t M = TBLSZ - 1u;
        const uint32_t hx0 = cx, hx1 = cx + 1u;
        const uint32_t hy0 = cy * P1, hy1 = hy0 + P1;
        const uint32_t hz0 = cz * P2, hz1 = hz0 + P2;
        c.i[0] = (hx0 ^ hy0 ^ hz0) & M; c.i[1] = (hx0 ^ hy0 ^ hz1) & M;
        c.i[2] = (hx0 ^ hy1 ^ hz0) & M; c.i[3] = (hx0 ^ hy1 ^ hz1) & M;
        c.i[4] = (hx1 ^ hy0 ^ hz0) & M; c.i[5] = (hx1 ^ hy0 ^ hz1) & M;
        c.i[6] = (hx1 ^ hy1 ^ hz0) & M; c.i[7] = (hx1 ^ hy1 ^ hz1) & M;
    }

    const float wx1 = tx, wx0 = 1.0f - tx;
    const float wy1 = ty, wy0 = 1.0f - ty;
    const float wz1 = tz, wz0 = 1.0f - tz;
    const float w00 = wx0 * wy0, w01 = wx0 * wy1;
    const float w10 = wx1 * wy0, w11 = wx1 * wy1;
    c.w[0] = w00 * wz0; c.w[1] = w00 * wz1;
    c.w[2] = w01 * wz0; c.w[3] = w01 * wz1;
    c.w[4] = w10 * wz0; c.w[5] = w10 * wz1;
    c.w[6] = w11 * wz0; c.w[7] = w11 * wz1;
}

// Weighted sum in the exact fmaf order of rounds 1-2 (bit-identical results).
__device__ __forceinline__ void wsum8(const Corner8& c, const float2* __restrict__ f,
                                      float& e0, float& e1)
{
    e0 = c.w[0] * f[0].x;
    e1 = c.w[0] * f[0].y;
    #pragma unroll
    for (int k = 1; k < 8; ++k) {
        e0 = fmaf(c.w[k], f[k].x, e0);
        e1 = fmaf(c.w[k], f[k].y, e1);
    }
}

// ---------------- Kernel A: level-blocked encode, 2 points/thread ----------------
// blockIdx.y = level; x-fastest dispatch keeps all resident blocks on ~one level,
// so that level's <=4MB table stays in the per-XCD L2.
__global__ __launch_bounds__(256)
void encode_level2(const float* __restrict__ x,
                   const float* __restrict__ tables,
                   float2* __restrict__ enc, int npts)
{
    const int l = blockIdx.y;
    const int t = blockIdx.x * 256 + threadIdx.x;
    const int n0 = 2 * t;
    if (n0 >= npts) return;
    const bool has1 = (n0 + 1) < npts;

    // 6 consecutive floats: point n0 = (a.x,a.y,b.x), point n0+1 = (b.y,c.x,c.y)
    const float2 a = *(const float2*)&x[6 * (size_t)t + 0];
    const float2 b = *(const float2*)&x[6 * (size_t)t + 2];
    const float2 c2 = has1 ? *(const float2*)&x[6 * (size_t)t + 4] : make_float2(0.f, 0.f);

    const float xA = (a.x + 1.0f) * 0.5f;
    const float yA = (a.y + 1.0f) * 0.5f;
    const float zA = (b.x + 1.0f) * 0.5f;
    const float xB = has1 ? (b.y + 1.0f) * 0.5f : xA;
    const float yB = has1 ? (c2.x + 1.0f) * 0.5f : yA;
    const float zB = has1 ? (c2.y + 1.0f) * 0.5f : zA;

    Corner8 A, B;
    corner_idx(l, xA, yA, zA, A);
    corner_idx(l, xB, yB, zB, B);

    const float2* tab = (const float2*)tables + (size_t)l * TBLSZ;
    // Issue all 16 gathers before consuming any -> 16 in flight per thread.
    float2 fA[8], fB[8];
    #pragma unroll
    for (int k = 0; k < 8; ++k) fA[k] = tab[A.i[k]];
    #pragma unroll
    for (int k = 0; k < 8; ++k) fB[k] = tab[B.i[k]];

    float eA0, eA1, eB0, eB1;
    wsum8(A, fA, eA0, eA1);
    wsum8(B, fB, eB0, eB1);

    const size_t base = (size_t)l * npts + n0;
    if (has1) {
        // 16B-aligned (l*npts and n0 both even); nontemporal: don't evict the table
        f32x4 v = {eA0, eA1, eB0, eB1};
        __builtin_nontemporal_store(v, (f32x4*)&enc[base]);
    } else {
        f32x2 v = {eA0, eA1};
        __builtin_nontemporal_store(v, (f32x2*)&enc[base]);
    }
}

// ---------------- Kernel B: MLP 32 -> 64 -> 64 -> 1, 2 points/thread ----------------
__global__ __launch_bounds__(256)
void mlp2(const float2* __restrict__ enc,
          const float* __restrict__ W0,
          const float* __restrict__ W1,
          const float* __restrict__ W2,
          float* __restrict__ out, int npts)
{
    __shared__ float sW0[ENCD * HID];   // [i][j], j contiguous
    __shared__ float sW1t[HID * HID];   // transposed: [j][i], i contiguous
    __shared__ float sW2[HID];

    const int tid = threadIdx.x;
    for (int idx = tid; idx < ENCD * HID; idx += 256) sW0[idx] = W0[idx];
    for (int idx = tid; idx < HID * HID; idx += 256) {
        const int j = idx >> 6, i = idx & 63;
        sW1t[idx] = W1[(i << 6) + j];
    }
    if (tid < HID) sW2[tid] = W2[tid];
    __syncthreads();

    const int t = blockIdx.x * 256 + tid;
    const int n0 = 2 * t;
    if (n0 >= npts) return;
    const bool has1 = (n0 + 1) < npts;

    float h1a[HID], h1b[HID];
    #pragma unroll
    for (int j = 0; j < HID; ++j) { h1a[j] = 0.0f; h1b[j] = 0.0f; }

    #pragma unroll
    for (int l = 0; l < NLVL; ++l) {
        const size_t base = (size_t)l * npts + n0;
        float4 e;
        if (has1) {
            e = *(const float4*)&enc[base];           // 16B aligned
        } else {
            const float2 ea = enc[base];
            e = make_float4(ea.x, ea.y, ea.x, ea.y);
        }
        const float* wr0 = &sW0[(2 * l) << 6];
        const float* wr1 = &sW0[(2 * l + 1) << 6];
        #pragma unroll
        for (int j = 0; j < HID; ++j) {
            const float w0j = wr0[j], w1j = wr1[j];
            h1a[j] = fmaf(e.x, w0j, fmaf(e.y, w1j, h1a[j]));
            h1b[j] = fmaf(e.z, w0j, fmaf(e.w, w1j, h1b[j]));
        }
    }
    #pragma unroll
    for (int j = 0; j < HID; ++j) {
        h1a[j] = fmaxf(h1a[j], 0.0f);
        h1b[j] = fmaxf(h1b[j], 0.0f);
    }

    float accA = 0.0f, accB = 0.0f;
    #pragma unroll
    for (int j = 0; j < HID; ++j) {
        const float* wr = &sW1t[j << 6];
        float a0 = 0.f, a1 = 0.f, a2 = 0.f, a3 = 0.f;
        float b0 = 0.f, b1 = 0.f, b2 = 0.f, b3 = 0.f;
        #pragma unroll
        for (int i = 0; i < HID; i += 4) {
            const float w0 = wr[i + 0], w1 = wr[i + 1], w2 = wr[i + 2], w3 = wr[i + 3];
            a0 = fmaf(h1a[i + 0], w0, a0); b0 = fmaf(h1b[i + 0], w0, b0);
            a1 = fmaf(h1a[i + 1], w1, a1); b1 = fmaf(h1b[i + 1], w1, b1);
            a2 = fmaf(h1a[i + 2], w2, a2); b2 = fmaf(h1b[i + 2], w2, b2);
            a3 = fmaf(h1a[i + 3], w3, a3); b3 = fmaf(h1b[i + 3], w3, b3);
        }
        const float ta = (a0 + a1) + (a2 + a3);
        const float tb = (b0 + b1) + (b2 + b3);
        const float w2j = sW2[j];
        accA = fmaf(fmaxf(ta, 0.0f), w2j, accA);
        accB = fmaf(fmaxf(tb, 0.0f), w2j, accB);
    }

    out[n0] = accA;
    if (has1) out[n0 + 1] = accB;
}

// ---------------- Fallback: round-1 fused kernel (if ws too small) ----------------
__global__ __launch_bounds__(256)
void sdf_fused(const float* __restrict__ x,
               const float* __restrict__ tables,
               const float* __restrict__ W0,
               const float* __restrict__ W1,
               const float* __restrict__ W2,
               float* __restrict__ out, int npts)
{
    __shared__ float sW0[ENCD * HID];
    __shared__ float sW1t[HID * HID];
    __shared__ float sW2[HID];

    const int tid = threadIdx.x;
    for (int idx = tid; idx < ENCD * HID; idx += 256) sW0[idx] = W0[idx];
    for (int idx = tid; idx < HID * HID; idx += 256) {
        const int j = idx >> 6, i = idx & 63;
        sW1t[idx] = W1[(i << 6) + j];
    }
    if (tid < HID) sW2[tid] = W2[tid];
    __syncthreads();

    const int n = blockIdx.x * 256 + tid;
    if (n >= npts) return;

    const float x01 = (x[3 * n + 0] + 1.0f) * 0.5f;
    const float y01 = (x[3 * n + 1] + 1.0f) * 0.5f;
    const float z01 = (x[3 * n + 2] + 1.0f) * 0.5f;

    float h1[HID];
    #pragma unroll
    for (int j = 0; j < HID; ++j) h1[j] = 0.0f;
    #pragma unroll
    for (int l = 0; l < NLVL; ++l) {
        Corner8 A;
        corner_idx(l, x01, y01, z01, A);
        const float2* tab = (const float2*)tables + (size_t)l * TBLSZ;
        float2 f[8];
        #pragma unroll
        for (int k = 0; k < 8; ++k) f[k] = tab[A.i[k]];
        float e0, e1;
        wsum8(A, f, e0, e1);
        const float* wr0 = &sW0[(2 * l) << 6];
        const float* wr1 = &sW0[(2 * l + 1) << 6];
        #pragma unroll
        for (int j = 0; j < HID; ++j)
            h1[j] = fmaf(e0, wr0[j], fmaf(e1, wr1[j], h1[j]));
    }
    #pragma unroll
    for (int j = 0; j < HID; ++j) h1[j] = fmaxf(h1[j], 0.0f);

    float acc = 0.0f;
    #pragma unroll
    for (int j = 0; j < HID; ++j) {
        const float* wr = &sW1t[j << 6];
        float t0 = 0.0f, t1 = 0.0f, t2 = 0.0f, t3 = 0.0f;
        #pragma unroll
        for (int i = 0; i < HID; i += 4) {
            t0 = fmaf(h1[i + 0], wr[i + 0], t0);
            t1 = fmaf(h1[i + 1], wr[i + 1], t1);
            t2 = fmaf(h1[i + 2], wr[i + 2], t2);
            t3 = fmaf(h1[i + 3], wr[i + 3], t3);
        }
        const float t = (t0 + t1) + (t2 + t3);
        acc = fmaf(fmaxf(t, 0.0f), sW2[j], acc);
    }
    out[n] = acc;
}

extern "C" void kernel_launch(void* const* d_in, const int* in_sizes, int n_in,
                              void* d_out, int out_size, void* d_ws, size_t ws_size,
                              hipStream_t stream) {
    const float* x      = (const float*)d_in[0];
    const float* tables = (const float*)d_in[1];
    const float* W0     = (const float*)d_in[2];
    const float* W1     = (const float*)d_in[3];
    const float* W2     = (const float*)d_in[4];
    float* out = (float*)d_out;

    const int npts = in_sizes[0] / 3;
    const size_t ws_needed = (size_t)NLVL * (size_t)npts * sizeof(float2);

    if (ws_size >= ws_needed) {
        float2* enc = (float2*)d_ws;
        const int npair = (npts + 1) / 2;
        dim3 grid((npair + 255) / 256, NLVL);
        encode_level2<<<grid, 256, 0, stream>>>(x, tables, enc, npts);
        mlp2<<<(npair + 255) / 256, 256, 0, stream>>>(enc, W0, W1, W2, out, npts);
    } else {
        sdf_fused<<<(npts + 255) / 256, 256, 0, stream>>>(x, tables, W0, W1, W2, out, npts);
    }
}

// Round 7
// 795.412 us; speedup vs baseline: 3.2347x; 3.2347x over previous
//
#include <hip/hip_runtime.h>
#include <stdint.h>

// SDFNetwork: instant-ngp hashgrid encode (L=16, F=2, T=2^19, base=16, scale=1.3819)
// + fully-fused MLP 32 -> 64 -> 64 -> 1 (bias-free, ReLU hidden, linear out), all fp32.
//
// Round 7: round-6 post-mortem showed mlp2 spilled (VGPR=256, 3GB scratch writes,
// occupancy 12%). New MLP: 1 pt/thread, weights read via wave-uniform scalar loads
// (s_load -> SGPR operand of v_fmac), no LDS, layer-2 j-blocked in halves to keep
// peak live regs ~100. Encode kernel unchanged (level-blocked, 2 pts/thread).

#define NLVL 16
#define TBLSZ (1u << 19)
#define HID 64
#define ENCD 32

typedef float f32x4 __attribute__((ext_vector_type(4)));
typedef float f32x2 __attribute__((ext_vector_type(2)));

// res_l = floor(16 * 1.3819^l); levels 0..4 are dense ((res+1)^3 <= T), 5..15 hashed.
__device__ constexpr int RES[NLVL] = {16, 22, 30, 42, 58, 80, 111, 153, 212, 294,
                                      406, 561, 775, 1072, 1481, 2047};

struct Corner8 {
    uint32_t i[8];
    float w[8];
};

__device__ __forceinline__ void corner_idx(int l, float x01, float y01, float z01,
                                           Corner8& c)
{
    const int res = RES[l];
    const float fres = (float)res;
    const float px = x01 * fres, py = y01 * fres, pz = z01 * fres;
    const float fx = floorf(px), fy = floorf(py), fz = floorf(pz);
    const float tx = px - fx, ty = py - fy, tz = pz - fz;
    const uint32_t cx = (uint32_t)fx, cy = (uint32_t)fy, cz = (uint32_t)fz;

    if (l < 5) {
        const uint32_t s1 = (uint32_t)(res + 1);
        const uint32_t s2 = s1 * s1;
        const uint32_t bx0 = cx, bx1 = cx + 1u;
        const uint32_t by0 = cy * s1, by1 = by0 + s1;
        const uint32_t bz0 = cz * s2, bz1 = bz0 + s2;
        c.i[0] = bx0 + by0 + bz0; c.i[1] = bx0 + by0 + bz1;
        c.i[2] = bx0 + by1 + bz0; c.i[3] = bx0 + by1 + bz1;
        c.i[4] = bx1 + by0 + bz0; c.i[5] = bx1 + by0 + bz1;
        c.i[6] = bx1 + by1 + bz0; c.i[7] = bx1 + by1 + bz1;
    } else {
        const uint32_t P1 = 2654435761u, P2 = 805459861u;
        const uint32_t M = TBLSZ - 1u;
        const uint32_t hx0 = cx, hx1 = cx + 1u;
        const uint32_t hy0 = cy * P1, hy1 = hy0 + P1;
        const uint32_t hz0 = cz * P2, hz1 = hz0 + P2;
        c.i[0] = (hx0 ^ hy0 ^ hz0) & M; c.i[1] = (hx0 ^ hy0 ^ hz1) & M;
        c.i[2] = (hx0 ^ hy1 ^ hz0) & M; c.i[3] = (hx0 ^ hy1 ^ hz1) & M;
        c.i[4] = (hx1 ^ hy0 ^ hz0) & M; c.i[5] = (hx1 ^ hy0 ^ hz1) & M;
        c.i[6] = (hx1 ^ hy1 ^ hz0) & M; c.i[7] = (hx1 ^ hy1 ^ hz1) & M;
    }

    const float wx1 = tx, wx0 = 1.0f - tx;
    const float wy1 = ty, wy0 = 1.0f - ty;
    const float wz1 = tz, wz0 = 1.0f - tz;
    const float w00 = wx0 * wy0, w01 = wx0 * wy1;
    const float w10 = wx1 * wy0, w11 = wx1 * wy1;
    c.w[0] = w00 * wz0; c.w[1] = w00 * wz1;
    c.w[2] = w01 * wz0; c.w[3] = w01 * wz1;
    c.w[4] = w10 * wz0; c.w[5] = w10 * wz1;
    c.w[6] = w11 * wz0; c.w[7] = w11 * wz1;
}

__device__ __forceinline__ void wsum8(const Corner8& c, const float2* __restrict__ f,
                                      float& e0, float& e1)
{
    e0 = c.w[0] * f[0].x;
    e1 = c.w[0] * f[0].y;
    #pragma unroll
    for (int k = 1; k < 8; ++k) {
        e0 = fmaf(c.w[k], f[k].x, e0);
        e1 = fmaf(c.w[k], f[k].y, e1);
    }
}

// ---------------- Kernel A: level-blocked encode, 2 points/thread ----------------
// blockIdx.y = level; x-fastest dispatch keeps all resident blocks on ~one level,
// so that level's <=4MB table stays in the per-XCD L2.
__global__ __launch_bounds__(256)
void encode_level2(const float* __restrict__ x,
                   const float* __restrict__ tables,
                   float2* __restrict__ enc, int npts)
{
    const int l = blockIdx.y;
    const int t = blockIdx.x * 256 + threadIdx.x;
    const int n0 = 2 * t;
    if (n0 >= npts) return;
    const bool has1 = (n0 + 1) < npts;

    const float2 a = *(const float2*)&x[6 * (size_t)t + 0];
    const float2 b = *(const float2*)&x[6 * (size_t)t + 2];
    const float2 c2 = has1 ? *(const float2*)&x[6 * (size_t)t + 4] : make_float2(0.f, 0.f);

    const float xA = (a.x + 1.0f) * 0.5f;
    const float yA = (a.y + 1.0f) * 0.5f;
    const float zA = (b.x + 1.0f) * 0.5f;
    const float xB = has1 ? (b.y + 1.0f) * 0.5f : xA;
    const float yB = has1 ? (c2.x + 1.0f) * 0.5f : yA;
    const float zB = has1 ? (c2.y + 1.0f) * 0.5f : zA;

    Corner8 A, B;
    corner_idx(l, xA, yA, zA, A);
    corner_idx(l, xB, yB, zB, B);

    const float2* tab = (const float2*)tables + (size_t)l * TBLSZ;
    float2 fA[8], fB[8];
    #pragma unroll
    for (int k = 0; k < 8; ++k) fA[k] = tab[A.i[k]];
    #pragma unroll
    for (int k = 0; k < 8; ++k) fB[k] = tab[B.i[k]];

    float eA0, eA1, eB0, eB1;
    wsum8(A, fA, eA0, eA1);
    wsum8(B, fB, eB0, eB1);

    const size_t base = (size_t)l * npts + n0;
    if (has1) {
        f32x4 v = {eA0, eA1, eB0, eB1};
        __builtin_nontemporal_store(v, (f32x4*)&enc[base]);
    } else {
        f32x2 v = {eA0, eA1};
        __builtin_nontemporal_store(v, (f32x2*)&enc[base]);
    }
}

// ---------------- Kernel B: MLP 32 -> 64 -> 64 -> 1, scalar-register weights ----
// 1 point/thread. All weight addresses are wave-uniform with compile-time offsets
// -> compiler emits s_load into SGPRs; v_fma uses the SGPR operand. No LDS.
// Layer 2 computed in two j-halves of 32 to cap peak live VGPRs (~h1[64]+h2[32]).
__global__ __launch_bounds__(256)
void mlp1(const float2* __restrict__ enc,
          const float* __restrict__ W0,
          const float* __restrict__ W1,
          const float* __restrict__ W2,
          float* __restrict__ out, int npts)
{
    const int n = blockIdx.x * 256 + threadIdx.x;
    if (n >= npts) return;

    // ---- Layer 1: h1 = enc @ W0 (relu applied on consumption) ----
    float h1[HID];
    #pragma unroll
    for (int j = 0; j < HID; ++j) h1[j] = 0.0f;

    #pragma unroll
    for (int l = 0; l < NLVL; ++l) {
        const f32x2 e = __builtin_nontemporal_load(
            (const f32x2*)&enc[(size_t)l * npts + n]);
        const float e0 = e.x, e1 = e.y;
        #pragma unroll
        for (int j4 = 0; j4 < HID / 4; ++j4) {
            const f32x4 w0 = *(const f32x4*)&W0[(2 * l) * HID + 4 * j4];
            const f32x4 w1 = *(const f32x4*)&W0[(2 * l + 1) * HID + 4 * j4];
            #pragma unroll
            for (int k = 0; k < 4; ++k)
                h1[4 * j4 + k] = fmaf(e0, w0[k], fmaf(e1, w1[k], h1[4 * j4 + k]));
        }
    }

    // ---- Layers 2+3 in two j-halves of 32 (caps live registers) ----
    float acc = 0.0f;
    #pragma unroll
    for (int jb = 0; jb < 2; ++jb) {
        float h2[HID / 2];
        #pragma unroll
        for (int j = 0; j < HID / 2; ++j) h2[j] = 0.0f;

        #pragma unroll
        for (int i = 0; i < HID; ++i) {
            const float a = fmaxf(h1[i], 0.0f);
            const float* wrow = &W1[i * HID + jb * (HID / 2)];
            #pragma unroll
            for (int j4 = 0; j4 < HID / 8; ++j4) {
                const f32x4 w = *(const f32x4*)&wrow[4 * j4];
                #pragma unroll
                for (int k = 0; k < 4; ++k)
                    h2[4 * j4 + k] = fmaf(a, w[k], h2[4 * j4 + k]);
            }
        }

        // layer 3 partial: acc += relu(h2) . W2[jb*32 .. jb*32+31]
        float p0 = 0.f, p1 = 0.f, p2 = 0.f, p3 = 0.f;
        #pragma unroll
        for (int j4 = 0; j4 < HID / 8; ++j4) {
            const f32x4 w = *(const f32x4*)&W2[jb * (HID / 2) + 4 * j4];
            p0 = fmaf(fmaxf(h2[4 * j4 + 0], 0.0f), w[0], p0);
            p1 = fmaf(fmaxf(h2[4 * j4 + 1], 0.0f), w[1], p1);
            p2 = fmaf(fmaxf(h2[4 * j4 + 2], 0.0f), w[2], p2);
            p3 = fmaf(fmaxf(h2[4 * j4 + 3], 0.0f), w[3], p3);
        }
        acc += (p0 + p1) + (p2 + p3);
    }

    out[n] = acc;
}

// ---------------- Fallback: round-1 fused kernel (if ws too small) ----------------
__global__ __launch_bounds__(256)
void sdf_fused(const float* __restrict__ x,
               const float* __restrict__ tables,
               const float* __restrict__ W0,
               const float* __restrict__ W1,
               const float* __restrict__ W2,
               float* __restrict__ out, int npts)
{
    __shared__ float sW0[ENCD * HID];
    __shared__ float sW1t[HID * HID];
    __shared__ float sW2[HID];

    const int tid = threadIdx.x;
    for (int idx = tid; idx < ENCD * HID; idx += 256) sW0[idx] = W0[idx];
    for (int idx = tid; idx < HID * HID; idx += 256) {
        const int j = idx >> 6, i = idx & 63;
        sW1t[idx] = W1[(i << 6) + j];
    }
    if (tid < HID) sW2[tid] = W2[tid];
    __syncthreads();

    const int n = blockIdx.x * 256 + tid;
    if (n >= npts) return;

    const float x01 = (x[3 * n + 0] + 1.0f) * 0.5f;
    const float y01 = (x[3 * n + 1] + 1.0f) * 0.5f;
    const float z01 = (x[3 * n + 2] + 1.0f) * 0.5f;

    float h1[HID];
    #pragma unroll
    for (int j = 0; j < HID; ++j) h1[j] = 0.0f;
    #pragma unroll
    for (int l = 0; l < NLVL; ++l) {
        Corner8 A;
        corner_idx(l, x01, y01, z01, A);
        const float2* tab = (const float2*)tables + (size_t)l * TBLSZ;
        float2 f[8];
        #pragma unroll
        for (int k = 0; k < 8; ++k) f[k] = tab[A.i[k]];
        float e0, e1;
        wsum8(A, f, e0, e1);
        const float* wr0 = &sW0[(2 * l) << 6];
        const float* wr1 = &sW0[(2 * l + 1) << 6];
        #pragma unroll
        for (int j = 0; j < HID; ++j)
            h1[j] = fmaf(e0, wr0[j], fmaf(e1, wr1[j], h1[j]));
    }
    #pragma unroll
    for (int j = 0; j < HID; ++j) h1[j] = fmaxf(h1[j], 0.0f);

    float acc = 0.0f;
    #pragma unroll
    for (int j = 0; j < HID; ++j) {
        const float* wr = &sW1t[j << 6];
        float t0 = 0.0f, t1 = 0.0f, t2 = 0.0f, t3 = 0.0f;
        #pragma unroll
        for (int i = 0; i < HID; i += 4) {
            t0 = fmaf(h1[i + 0], wr[i + 0], t0);
            t1 = fmaf(h1[i + 1], wr[i + 1], t1);
            t2 = fmaf(h1[i + 2], wr[i + 2], t2);
            t3 = fmaf(h1[i + 3], wr[i + 3], t3);
        }
        const float t = (t0 + t1) + (t2 + t3);
        acc = fmaf(fmaxf(t, 0.0f), sW2[j], acc);
    }
    out[n] = acc;
}

extern "C" void kernel_launch(void* const* d_in, const int* in_sizes, int n_in,
                              void* d_out, int out_size, void* d_ws, size_t ws_size,
                              hipStream_t stream) {
    const float* x      = (const float*)d_in[0];
    const float* tables = (const float*)d_in[1];
    const float* W0     = (const float*)d_in[2];
    const float* W1     = (const float*)d_in[3];
    const float* W2     = (const float*)d_in[4];
    float* out = (float*)d_out;

    const int npts = in_sizes[0] / 3;
    const size_t ws_needed = (size_t)NLVL * (size_t)npts * sizeof(float2);

    if (ws_size >= ws_needed) {
        float2* enc = (float2*)d_ws;
        const int npair = (npts + 1) / 2;
        dim3 grid((npair + 255) / 256, NLVL);
        encode_level2<<<grid, 256, 0, stream>>>(x, tables, enc, npts);
        mlp1<<<(npts + 255) / 256, 256, 0, stream>>>(enc, W0, W1, W2, out, npts);
    } else {
        sdf_fused<<<(npts + 255) / 256, 256, 0, stream>>>(x, tables, W0, W1, W2, out, npts);
    }
}

// Round 8
// 634.775 us; speedup vs baseline: 4.0533x; 1.2531x over previous
//
#include <hip/hip_runtime.h>
#include <stdint.h>

// SDFNetwork: instant-ngp hashgrid encode (L=16, F=2, T=2^19, base=16, scale=1.3819)
// + fully-fused MLP 32 -> 64 -> 64 -> 1 (bias-free, ReLU hidden, linear out), all fp32.
//
// Round 8:
//  - encode: corner-pair gathers. x0/x1 corners are index-adjacent when
//    (i000^i100)==1 (dense: i000 even; hashed: cx even) -> one aligned 16B load
//    fetches both corners. Cuts per-lane TA addresses 8 -> ~6.
//  - MLP: 2 pts/thread with SGPR weights, layer-2 j-quarter blocking to cap
//    live VGPRs (~175, no spill), halving per-point scalar-load traffic.

#define NLVL 16
#define TBLSZ (1u << 19)
#define HID 64
#define ENCD 32

typedef float f32x4 __attribute__((ext_vector_type(4)));
typedef float f32x2 __attribute__((ext_vector_type(2)));

// res_l = floor(16 * 1.3819^l); levels 0..4 are dense ((res+1)^3 <= T), 5..15 hashed.
__device__ constexpr int RES[NLVL] = {16, 22, 30, 42, 58, 80, 111, 153, 212, 294,
                                      406, 561, 775, 1072, 1481, 2047};

struct Corner8 {
    uint32_t i[8];
    float w[8];
};

__device__ __forceinline__ void corner_idx(int l, float x01, float y01, float z01,
                                           Corner8& c)
{
    const int res = RES[l];
    const float fres = (float)res;
    const float px = x01 * fres, py = y01 * fres, pz = z01 * fres;
    const float fx = floorf(px), fy = floorf(py), fz = floorf(pz);
    const float tx = px - fx, ty = py - fy, tz = pz - fz;
    const uint32_t cx = (uint32_t)fx, cy = (uint32_t)fy, cz = (uint32_t)fz;

    if (l < 5) {
        const uint32_t s1 = (uint32_t)(res + 1);
        const uint32_t s2 = s1 * s1;
        const uint32_t bx0 = cx, bx1 = cx + 1u;
        const uint32_t by0 = cy * s1, by1 = by0 + s1;
        const uint32_t bz0 = cz * s2, bz1 = bz0 + s2;
        c.i[0] = bx0 + by0 + bz0; c.i[1] = bx0 + by0 + bz1;
        c.i[2] = bx0 + by1 + bz0; c.i[3] = bx0 + by1 + bz1;
        c.i[4] = bx1 + by0 + bz0; c.i[5] = bx1 + by0 + bz1;
        c.i[6] = bx1 + by1 + bz0; c.i[7] = bx1 + by1 + bz1;
    } else {
        const uint32_t P1 = 2654435761u, P2 = 805459861u;
        const uint32_t M = TBLSZ - 1u;
        const uint32_t hx0 = cx, hx1 = cx + 1u;
        const uint32_t hy0 = cy * P1, hy1 = hy0 + P1;
        const uint32_t hz0 = cz * P2, hz1 = hz0 + P2;
        c.i[0] = (hx0 ^ hy0 ^ hz0) & M; c.i[1] = (hx0 ^ hy0 ^ hz1) & M;
        c.i[2] = (hx0 ^ hy1 ^ hz0) & M; c.i[3] = (hx0 ^ hy1 ^ hz1) & M;
        c.i[4] = (hx1 ^ hy0 ^ hz0) & M; c.i[5] = (hx1 ^ hy0 ^ hz1) & M;
        c.i[6] = (hx1 ^ hy1 ^ hz0) & M; c.i[7] = (hx1 ^ hy1 ^ hz1) & M;
    }

    const float wx1 = tx, wx0 = 1.0f - tx;
    const float wy1 = ty, wy0 = 1.0f - ty;
    const float wz1 = tz, wz0 = 1.0f - tz;
    const float w00 = wx0 * wy0, w01 = wx0 * wy1;
    const float w10 = wx1 * wy0, w11 = wx1 * wy1;
    c.w[0] = w00 * wz0; c.w[1] = w00 * wz1;
    c.w[2] = w01 * wz0; c.w[3] = w01 * wz1;
    c.w[4] = w10 * wz0; c.w[5] = w10 * wz1;
    c.w[6] = w11 * wz0; c.w[7] = w11 * wz1;
}

// Gather the 8 corners; pairs (p, p+4) differ only in x. When their indices are
// bitwise-adjacent ((i0^i1)==1), one aligned 16B load fetches both corners.
__device__ __forceinline__ void gather8(const Corner8& c, const float2* __restrict__ tab,
                                        float2 f[8])
{
    #pragma unroll
    for (int p = 0; p < 4; ++p) {
        const uint32_t i0 = c.i[p], i1 = c.i[p + 4];
        if ((i0 ^ i1) == 1u) {
            const f32x4 q = *(const f32x4*)&tab[i0 & ~1u];   // 16B aligned
            if (i0 & 1u) {
                f[p]     = make_float2(q.z, q.w);
                f[p + 4] = make_float2(q.x, q.y);
            } else {
                f[p]     = make_float2(q.x, q.y);
                f[p + 4] = make_float2(q.z, q.w);
            }
        } else {
            f[p]     = tab[i0];
            f[p + 4] = tab[i1];
        }
    }
}

// Weighted sum in the exact fmaf order of rounds 1-7.
__device__ __forceinline__ void wsum8(const Corner8& c, const float2* __restrict__ f,
                                      float& e0, float& e1)
{
    e0 = c.w[0] * f[0].x;
    e1 = c.w[0] * f[0].y;
    #pragma unroll
    for (int k = 1; k < 8; ++k) {
        e0 = fmaf(c.w[k], f[k].x, e0);
        e1 = fmaf(c.w[k], f[k].y, e1);
    }
}

// ---------------- Kernel A: level-blocked encode, 2 points/thread ----------------
// blockIdx.y = level; x-fastest dispatch keeps all resident blocks on ~one level,
// so that level's <=4MB table stays in the per-XCD L2.
__global__ __launch_bounds__(256)
void encode_level2(const float* __restrict__ x,
                   const float* __restrict__ tables,
                   float2* __restrict__ enc, int npts)
{
    const int l = blockIdx.y;
    const int t = blockIdx.x * 256 + threadIdx.x;
    const int n0 = 2 * t;
    if (n0 >= npts) return;
    const bool has1 = (n0 + 1) < npts;

    const float2 a = *(const float2*)&x[6 * (size_t)t + 0];
    const float2 b = *(const float2*)&x[6 * (size_t)t + 2];
    const float2 c2 = has1 ? *(const float2*)&x[6 * (size_t)t + 4] : make_float2(0.f, 0.f);

    const float xA = (a.x + 1.0f) * 0.5f;
    const float yA = (a.y + 1.0f) * 0.5f;
    const float zA = (b.x + 1.0f) * 0.5f;
    const float xB = has1 ? (b.y + 1.0f) * 0.5f : xA;
    const float yB = has1 ? (c2.x + 1.0f) * 0.5f : yA;
    const float zB = has1 ? (c2.y + 1.0f) * 0.5f : zA;

    Corner8 A, B;
    corner_idx(l, xA, yA, zA, A);
    corner_idx(l, xB, yB, zB, B);

    const float2* tab = (const float2*)tables + (size_t)l * TBLSZ;
    float2 fA[8], fB[8];
    gather8(A, tab, fA);
    gather8(B, tab, fB);

    float eA0, eA1, eB0, eB1;
    wsum8(A, fA, eA0, eA1);
    wsum8(B, fB, eB0, eB1);

    const size_t base = (size_t)l * npts + n0;
    if (has1) {
        f32x4 v = {eA0, eA1, eB0, eB1};
        __builtin_nontemporal_store(v, (f32x4*)&enc[base]);
    } else {
        f32x2 v = {eA0, eA1};
        __builtin_nontemporal_store(v, (f32x2*)&enc[base]);
    }
}

// ---------------- Kernel B: MLP 32 -> 64 -> 64 -> 1, 2 pts/thread, SGPR weights --
// Weight addresses are wave-uniform -> s_load into SGPRs; v_fma uses the SGPR
// operand. No LDS. Layer 2 in j-quarters (h2=16/pt) caps live VGPRs (~175).
// Level loop unroll 1 stops the compiler hoisting all 16 enc loads at once.
__global__ __launch_bounds__(256)
void mlp2s(const float2* __restrict__ enc,
           const float* __restrict__ W0,
           const float* __restrict__ W1,
           const float* __restrict__ W2,
           float* __restrict__ out, int npts)
{
    const int t = blockIdx.x * 256 + threadIdx.x;
    const int n0 = 2 * t;
    if (n0 >= npts) return;
    const bool has1 = (n0 + 1) < npts;

    float h1a[HID], h1b[HID];
    #pragma unroll
    for (int j = 0; j < HID; ++j) { h1a[j] = 0.0f; h1b[j] = 0.0f; }

    #pragma unroll 1
    for (int l = 0; l < NLVL; ++l) {
        f32x4 e;
        if (has1) {
            e = __builtin_nontemporal_load((const f32x4*)&enc[(size_t)l * npts + n0]);
        } else {
            const f32x2 ea = __builtin_nontemporal_load(
                (const f32x2*)&enc[(size_t)l * npts + n0]);
            e.x = ea.x; e.y = ea.y; e.z = ea.x; e.w = ea.y;
        }
        #pragma unroll
        for (int j4 = 0; j4 < HID / 4; ++j4) {
            const f32x4 w0 = *(const f32x4*)&W0[(2 * l) * HID + 4 * j4];
            const f32x4 w1 = *(const f32x4*)&W0[(2 * l + 1) * HID + 4 * j4];
            #pragma unroll
            for (int k = 0; k < 4; ++k) {
                h1a[4 * j4 + k] = fmaf(e.x, w0[k], fmaf(e.y, w1[k], h1a[4 * j4 + k]));
                h1b[4 * j4 + k] = fmaf(e.z, w0[k], fmaf(e.w, w1[k], h1b[4 * j4 + k]));
            }
        }
    }

    // relu in place (reused across all 4 j-blocks)
    #pragma unroll
    for (int j = 0; j < HID; ++j) {
        h1a[j] = fmaxf(h1a[j], 0.0f);
        h1b[j] = fmaxf(h1b[j], 0.0f);
    }

    float accA = 0.0f, accB = 0.0f;
    #pragma unroll 1
    for (int jb = 0; jb < 4; ++jb) {
        float h2a[HID / 4], h2b[HID / 4];
        #pragma unroll
        for (int j = 0; j < HID / 4; ++j) { h2a[j] = 0.0f; h2b[j] = 0.0f; }

        #pragma unroll
        for (int i = 0; i < HID; ++i) {
            const float ra = h1a[i], rb = h1b[i];
            const float* wrow = &W1[i * HID + jb * (HID / 4)];
            #pragma unroll
            for (int j4 = 0; j4 < HID / 16; ++j4) {
                const f32x4 w = *(const f32x4*)&wrow[4 * j4];
                #pragma unroll
                for (int k = 0; k < 4; ++k) {
                    h2a[4 * j4 + k] = fmaf(ra, w[k], h2a[4 * j4 + k]);
                    h2b[4 * j4 + k] = fmaf(rb, w[k], h2b[4 * j4 + k]);
                }
            }
        }

        #pragma unroll
        for (int j4 = 0; j4 < HID / 16; ++j4) {
            const f32x4 w = *(const f32x4*)&W2[jb * (HID / 4) + 4 * j4];
            #pragma unroll
            for (int k = 0; k < 4; ++k) {
                accA = fmaf(fmaxf(h2a[4 * j4 + k], 0.0f), w[k], accA);
                accB = fmaf(fmaxf(h2b[4 * j4 + k], 0.0f), w[k], accB);
            }
        }
    }

    out[n0] = accA;
    if (has1) out[n0 + 1] = accB;
}

// ---------------- Fallback: fused kernel (if ws too small) ----------------
__global__ __launch_bounds__(256)
void sdf_fused(const float* __restrict__ x,
               const float* __restrict__ tables,
               const float* __restrict__ W0,
               const float* __restrict__ W1,
               const float* __restrict__ W2,
               float* __restrict__ out, int npts)
{
    __shared__ float sW0[ENCD * HID];
    __shared__ float sW1t[HID * HID];
    __shared__ float sW2[HID];

    const int tid = threadIdx.x;
    for (int idx = tid; idx < ENCD * HID; idx += 256) sW0[idx] = W0[idx];
    for (int idx = tid; idx < HID * HID; idx += 256) {
        const int j = idx >> 6, i = idx & 63;
        sW1t[idx] = W1[(i << 6) + j];
    }
    if (tid < HID) sW2[tid] = W2[tid];
    __syncthreads();

    const int n = blockIdx.x * 256 + tid;
    if (n >= npts) return;

    const float x01 = (x[3 * n + 0] + 1.0f) * 0.5f;
    const float y01 = (x[3 * n + 1] + 1.0f) * 0.5f;
    const float z01 = (x[3 * n + 2] + 1.0f) * 0.5f;

    float h1[HID];
    #pragma unroll
    for (int j = 0; j < HID; ++j) h1[j] = 0.0f;
    #pragma unroll
    for (int l = 0; l < NLVL; ++l) {
        Corner8 A;
        corner_idx(l, x01, y01, z01, A);
        const float2* tab = (const float2*)tables + (size_t)l * TBLSZ;
        float2 f[8];
        gather8(A, tab, f);
        float e0, e1;
        wsum8(A, f, e0, e1);
        const float* wr0 = &sW0[(2 * l) << 6];
        const float* wr1 = &sW0[(2 * l + 1) << 6];
        #pragma unroll
        for (int j = 0; j < HID; ++j)
            h1[j] = fmaf(e0, wr0[j], fmaf(e1, wr1[j], h1[j]));
    }
    #pragma unroll
    for (int j = 0; j < HID; ++j) h1[j] = fmaxf(h1[j], 0.0f);

    float acc = 0.0f;
    #pragma unroll
    for (int j = 0; j < HID; ++j) {
        const float* wr = &sW1t[j << 6];
        float t0 = 0.0f, t1 = 0.0f, t2 = 0.0f, t3 = 0.0f;
        #pragma unroll
        for (int i = 0; i < HID; i += 4) {
            t0 = fmaf(h1[i + 0], wr[i + 0], t0);
            t1 = fmaf(h1[i + 1], wr[i + 1], t1);
            t2 = fmaf(h1[i + 2], wr[i + 2], t2);
            t3 = fmaf(h1[i + 3], wr[i + 3], t3);
        }
        const float t = (t0 + t1) + (t2 + t3);
        acc = fmaf(fmaxf(t, 0.0f), sW2[j], acc);
    }
    out[n] = acc;
}

extern "C" void kernel_launch(void* const* d_in, const int* in_sizes, int n_in,
                              void* d_out, int out_size, void* d_ws, size_t ws_size,
                              hipStream_t stream) {
    const float* x      = (const float*)d_in[0];
    const float* tables = (const float*)d_in[1];
    const float* W0     = (const float*)d_in[2];
    const float* W1     = (const float*)d_in[3];
    const float* W2     = (const float*)d_in[4];
    float* out = (float*)d_out;

    const int npts = in_sizes[0] / 3;
    const size_t ws_needed = (size_t)NLVL * (size_t)npts * sizeof(float2);

    if (ws_size >= ws_needed) {
        float2* enc = (float2*)d_ws;
        const int npair = (npts + 1) / 2;
        dim3 grid((npair + 255) / 256, NLVL);
        encode_level2<<<grid, 256, 0, stream>>>(x, tables, enc, npts);
        mlp2s<<<(npair + 255) / 256, 256, 0, stream>>>(enc, W0, W1, W2, out, npts);
    } else {
        sdf_fused<<<(npts + 255) / 256, 256, 0, stream>>>(x, tables, W0, W1, W2, out, npts);
    }
}